// Round 11
// baseline (1004.916 us; speedup 1.0000x reference)
//
#include <hip/hip_runtime.h>
#include <cstdint>
#include <cstddef>

#define N_TOK 8192
#define DM 1024
#define DFF 4096
#define NE 8
#define PAD 256
#define CAP (N_TOK * 2 + NE * PAD)  // 18432

typedef __attribute__((ext_vector_type(8))) short bf16x8;
typedef __attribute__((ext_vector_type(4))) float f32x4;

__device__ __forceinline__ unsigned short f2bf(float f) {
  union { float f; unsigned u; } v; v.f = f;
  unsigned r = v.u + 0x7FFFu + ((v.u >> 16) & 1u);
  return (unsigned short)(r >> 16);
}
__device__ __forceinline__ float bf2f(unsigned short h) {
  union { unsigned u; float f; } v; v.u = ((unsigned)h) << 16;
  return v.f;
}

__device__ __forceinline__ void async16(unsigned short* l, const unsigned short* g) {
  __builtin_amdgcn_global_load_lds(
      (const __attribute__((address_space(1))) unsigned int*)g,
      (__attribute__((address_space(3))) unsigned int*)l, 16, 0, 0);
}

// ---------------- init ----------------
__global__ void init_kernel(unsigned* counts, float* Psum) {
  int i = threadIdx.x;
  if (i < NE) { counts[i] = 0u; Psum[i] = 0.f; }
}

// ---------------- transpose + fp32->bf16 convert ----------------
__global__ __launch_bounds__(256) void transpose_cvt(
    const float* __restrict__ in, unsigned short* __restrict__ out, int R, int C) {
  __shared__ float tile[64][65];
  const float* I = in + (size_t)blockIdx.z * R * C;
  unsigned short* O = out + (size_t)blockIdx.z * R * C;
  const int r0 = blockIdx.y * 64, c0 = blockIdx.x * 64;
  const int c = threadIdx.x & 63, r4 = threadIdx.x >> 6;
#pragma unroll
  for (int i = 0; i < 16; ++i) {
    int r = r4 * 16 + i;
    tile[r][c] = I[(size_t)(r0 + r) * C + c0 + c];
  }
  __syncthreads();
#pragma unroll
  for (int i = 0; i < 16; ++i) {
    int r = r4 * 16 + i;
    O[(size_t)(c0 + r) * R + r0 + c] = f2bf(tile[c][r]);
  }
}

// ---------------- router ----------------
__global__ __launch_bounds__(256) void router_kernel(
    const float* __restrict__ x, const float* __restrict__ Wr,
    unsigned* __restrict__ counts, float* __restrict__ Psum,
    int* __restrict__ tok_e, float* __restrict__ tok_g, int* __restrict__ tok_ls) {
  __shared__ float ps[NE];
  const int tid = threadIdx.x;
  if (tid < NE) ps[tid] = 0.f;
  __syncthreads();
  const int lane = tid & 63, wid = tid >> 6;
  for (int u = 0; u < 4; ++u) {
    const int t = blockIdx.x * 16 + wid * 4 + u;
    float a[NE];
#pragma unroll
    for (int e = 0; e < NE; ++e) a[e] = 0.f;
#pragma unroll
    for (int i = 0; i < 16; ++i) {
      const int d = i * 64 + lane;
      const float xv = x[(size_t)t * DM + d];
      const float* wr = &Wr[(size_t)d * NE];
#pragma unroll
      for (int e = 0; e < NE; ++e) a[e] = fmaf(xv, wr[e], a[e]);
    }
#pragma unroll
    for (int e = 0; e < NE; ++e)
      for (int s = 32; s > 0; s >>= 1) a[e] += __shfl_xor(a[e], s);
    float mx = a[0];
#pragma unroll
    for (int e = 1; e < NE; ++e) mx = fmaxf(mx, a[e]);
    float p[NE], s = 0.f;
#pragma unroll
    for (int e = 0; e < NE; ++e) { p[e] = expf(a[e] - mx); s += p[e]; }
    float q[NE];
#pragma unroll
    for (int e = 0; e < NE; ++e) q[e] = p[e] / s;
    int i0 = 0; float b0 = q[0];
#pragma unroll
    for (int e = 1; e < NE; ++e) if (q[e] > b0) { b0 = q[e]; i0 = e; }
    int i1 = -1; float b1v = -1.f;
#pragma unroll
    for (int e = 0; e < NE; ++e) if (e != i0 && q[e] > b1v) { b1v = q[e]; i1 = e; }
    const float gs = q[i0] + q[i1];
    const float g0 = q[i0] / gs, g1 = q[i1] / gs;
    if (lane == 0) {
#pragma unroll
      for (int e = 0; e < NE; ++e) atomicAdd(&ps[e], q[e]);
      const int ls0 = (int)atomicAdd(&counts[i0], 1u);
      const int ls1 = (int)atomicAdd(&counts[i1], 1u);
      tok_e[2 * t] = i0; tok_e[2 * t + 1] = i1;
      tok_g[2 * t] = g0; tok_g[2 * t + 1] = g1;
      tok_ls[2 * t] = ls0; tok_ls[2 * t + 1] = ls1;
    }
  }
  __syncthreads();
  if (tid < NE) atomicAdd(&Psum[tid], ps[tid]);
}

// ---------------- offsets (256-padded prefix) + total + aux loss ----------------
__global__ void offsets_kernel(const unsigned* __restrict__ counts,
                               const float* __restrict__ Psum,
                               int* __restrict__ offs, float* __restrict__ aux_out) {
  if (threadIdx.x == 0 && blockIdx.x == 0) {
    int o = 0; float aux = 0.f;
    for (int e = 0; e < NE; ++e) {
      offs[e] = o;
      o += (int)((counts[e] + (PAD - 1u)) / PAD) * PAD;
      aux += ((float)counts[e] / (float)N_TOK) * (Psum[e] / (float)N_TOK);
    }
    offs[NE] = o;  // total padded rows
    aux_out[0] = 0.01f * (float)NE * aux;
  }
}

// ---------------- gather ----------------
__global__ __launch_bounds__(256) void gather_kernel(
    const float* __restrict__ x, const int* __restrict__ tok_e,
    const int* __restrict__ tok_ls, const int* __restrict__ offs,
    int* __restrict__ tok_slot, unsigned short* __restrict__ Xg) {
  const int t = blockIdx.x;
  __shared__ int ss[2];
  if (threadIdx.x < 2) {
    const int k = threadIdx.x;
    const int e = tok_e[2 * t + k];
    const int sl = offs[e] + tok_ls[2 * t + k];
    ss[k] = sl;
    tok_slot[2 * t + k] = sl;
  }
  __syncthreads();
  const int i = threadIdx.x;
  const float4 v = ((const float4*)x)[(size_t)t * 256 + i];
  ushort4 h;
  h.x = f2bf(v.x); h.y = f2bf(v.y); h.z = f2bf(v.z); h.w = f2bf(v.w);
  ((ushort4*)Xg)[(size_t)ss[0] * 256 + i] = h;
  ((ushort4*)Xg)[(size_t)ss[1] * 256 + i] = h;
}

// ---------------- GEMM: A direct global->VGPR, B via LDS ring-3 --------------
// R11 change: A fragments are loaded STRAIGHT from global (affine per-lane addr,
// 16 rows x 64B segments, L1-resident panel reused by wm-sharing waves) -- LDS
// traffic per block-tile drops 88KB -> 48KB (no A stage writes, half the reads);
// the previously-idle L1/TCP pipe carries A in parallel with LDS carrying B.
// BMODE 0: BM=256,BN=128,TN=32,SPLIT=1,S=1 (GEMM1). BMODE 1: BM=128,BN=256,
// TN=4,SPLIT=2,S=2 (GEMM2). 512 thr = 8 waves, wave tile 64x64, acc 64 AGPR ->
// ~124 regs/wave => 4 waves/SIMD, 2 blocks/CU (TLP lever from R8 preserved).
// Per-tile per-wave ledger: [afr x4 global] [stgB(d2,T+2) xS] [vmcnt(S)]
// [bfr x4 LDS] [16 MFMA] [barrier]. vmcnt(S) retires own stgB(T+1) + afr,
// leaves stgB(T+2) in flight (counted, never 0 in-loop). Cross-wave: wave W's
// stgB(T) retired by W's vmcnt at tile T-1, >=1 barrier before any wave reads
// region T (same proof shape as R8-R10, absmax-validated).
// XCD-banded flat grid (R10) retained. tanh-GELU (R10) retained.
template <int BMODE, bool GELU, typename CT>
__global__ __launch_bounds__(512, 4) void gemmk(
    const unsigned short* __restrict__ Ag, const unsigned short* __restrict__ Bt,
    const float* __restrict__ bias, CT* __restrict__ Cout,
    const int* __restrict__ offs, const int K, const int Nn,
    const size_t c_split_stride) {
  constexpr int BM = (BMODE == 0) ? 256 : 128;
  constexpr int BN = (BMODE == 0) ? 128 : 256;
  constexpr int WN = BN / 64;                  // waves along N
  constexpr int BREG = BN * 32;                // shorts per B ring entry
  constexpr int SPLIT = (BMODE == 0) ? 1 : 2;
  constexpr int S = (BMODE == 0) ? 1 : 2;      // async16 calls per stgB

  // flat decode (all power-of-2 fields); XCD-banded by gr%8
  const int flat = (int)blockIdx.x;
  const int xr = flat & 7;
  const int rest = flat >> 3;
  int tn, gr, ks;
  if (BMODE == 0) { tn = rest & 31; ks = 0; gr = ((rest >> 5) << 3) + xr; }
  else            { tn = rest & 3; ks = (rest >> 2) & 1; gr = ((rest >> 3) << 3) + xr; }

  const int grow = gr * BM;
  if (grow >= offs[NE]) return;
  int e = 0;
#pragma unroll
  for (int k = 1; k < NE; ++k) if (offs[k] <= grow) e = k;
  const int kext = K / SPLIT;
  const int nt = kext >> 5;  // K-tiles of 32

  const unsigned short* A = Ag + (size_t)grow * K + (size_t)ks * kext;
  const unsigned short* B = Bt + ((size_t)e * Nn + (size_t)tn * BN) * K + (size_t)ks * kext;
  const float* bp = (ks == 0) ? bias : nullptr;
  CT* Cw = Cout + (size_t)ks * c_split_stride;

  extern __shared__ unsigned short lds[];
  unsigned short* LB = lds;                  // 3 x BREG

  const int tid = threadIdx.x;
  const int lane = tid & 63;
  const int wid = tid >> 6;
  const int wm = wid / WN;
  const int wn = wid % WN;
  const int arow = lane & 15;
  const int kc = lane >> 4;   // 16B chunk 0..3 within 32-short row

  // B LDS read addressing: swizzled chunk (kc ^ ((row>>1)&3)); row%8 == arow%8.
  const int sc = ((kc ^ ((arow >> 1) & 3)) << 3);
  const int bBase = (wn * 64 + arow) * 32 + sc;   // + nf*512

  // A direct per-lane fragment pointers: afr[mf] lanes (arow,kc) read
  // A[wm*64+mf*16+arow][T*32 + kc*8 .. +8]  (matches staged-path layout).
  const unsigned short* Arow[4];
#pragma unroll
  for (int mf = 0; mf < 4; ++mf)
    Arow[mf] = A + (size_t)(wm * 64 + mf * 16 + arow) * K + kc * 8;

  // B stage addressing: chunk c = call*512 + tid; r = c>>2; src chunk
  // (tid&3)^((r>>1)&3) = (tid&3)^((tid>>3)&3) (call adds 128 rows = 0 mod 8).
  const int swzs = (((tid & 3) ^ ((tid >> 3) & 3)) << 3);
  const unsigned short* sB = B + (size_t)(tid >> 2) * K + swzs;
  const size_t r128 = (size_t)128 * K;
  const size_t dstw = (size_t)wid * 512;  // shorts; lane*16B added by HW

  auto stgB = [&](int db, size_t kt) {
    async16(LB + db * BREG + dstw, sB + kt);
    if constexpr (BMODE == 1) async16(LB + db * BREG + 4096 + dstw, sB + r128 + kt);
  };

  f32x4 acc[4][4];
#pragma unroll
  for (int m = 0; m < 4; ++m)
#pragma unroll
    for (int n = 0; n < 4; ++n) acc[m][n] = (f32x4){0.f, 0.f, 0.f, 0.f};

  // prologue: stage B(T0)->buf0, B(T1)->buf1; own-wave wait + barrier.
  stgB(0, 0);
  stgB(1, 32);
  asm volatile("s_waitcnt vmcnt(%0)" ::"i"(S) : "memory");
  asm volatile("s_barrier" ::: "memory");

  int d0 = 0;
  size_t Tk = 0;
  for (int T = 0; T < nt; ++T) {
    const int d2 = (d0 >= 1) ? d0 - 1 : d0 + 2;  // (d0+2)%3
    const size_t kt2 = (size_t)((T + 2 < nt) ? T + 2 : 0) << 5;
    const int lb = d0 * BREG;

    bf16x8 afr[4], bfr[4];
#pragma unroll
    for (int mf = 0; mf < 4; ++mf) afr[mf] = *(const bf16x8*)(Arow[mf] + Tk);
    stgB(d2, kt2);
    asm volatile("s_waitcnt vmcnt(%0)" ::"i"(S) : "memory");
#pragma unroll
    for (int nf = 0; nf < 4; ++nf) bfr[nf] = *(const bf16x8*)&LB[lb + bBase + nf * 512];

    __builtin_amdgcn_s_setprio(1);
#pragma unroll
    for (int m = 0; m < 4; ++m)
#pragma unroll
      for (int n = 0; n < 4; ++n)
        acc[m][n] = __builtin_amdgcn_mfma_f32_16x16x32_bf16(afr[m], bfr[n], acc[m][n], 0, 0, 0);
    __builtin_amdgcn_s_setprio(0);

    asm volatile("s_barrier" ::: "memory");
    d0 = (d0 == 2) ? 0 : d0 + 1;
    Tk += 32;
  }
  asm volatile("s_waitcnt vmcnt(0)" ::: "memory");

  // epilogue: n innermost -> each output line completed back-to-back (no RMW).
  const int rl = (lane >> 4) * 4;
  const int cl = lane & 15;
  float bv[4];
#pragma unroll
  for (int n = 0; n < 4; ++n) {
    const int col = tn * BN + wn * 64 + n * 16 + cl;
    bv[n] = bp ? bp[(size_t)e * Nn + col] : 0.f;
  }
#pragma unroll
  for (int m = 0; m < 4; ++m) {
    const int row = grow + wm * 64 + m * 16 + rl;
#pragma unroll
    for (int jj = 0; jj < 4; ++jj) {
      CT* rowp = Cw + (size_t)(row + jj) * Nn + tn * BN + wn * 64 + cl;
#pragma unroll
      for (int n = 0; n < 4; ++n) {
        float v = acc[m][n][jj] + bv[n];
        if (GELU) {
          // tanh-approx GELU, sigmoid form (inf-safe)
          const float w = -1.5957691216057308f * (v + 0.044715f * v * v * v);
          v = v / (1.f + __expf(w));
        }
        if constexpr (sizeof(CT) == 2) { rowp[n * 16] = (CT)f2bf(v); } else { rowp[n * 16] = (CT)v; }
      }
    }
  }
}

// ---------------- combine: out[t] = g0*(Ya+Yb)[s0] + g1*(Ya+Yb)[s1], Y bf16 --
__global__ __launch_bounds__(256) void combine_kernel(
    const unsigned short* __restrict__ Ya, const unsigned short* __restrict__ Yb,
    const int* __restrict__ tok_slot, const float* __restrict__ tok_g,
    float* __restrict__ out) {
  const int t = blockIdx.x;
  const int i = threadIdx.x;
  const int s0 = tok_slot[2 * t], s1 = tok_slot[2 * t + 1];
  const float g0 = tok_g[2 * t], g1 = tok_g[2 * t + 1];
  const ushort4 a0 = ((const ushort4*)Ya)[(size_t)s0 * 256 + i];
  const ushort4 b0 = ((const ushort4*)Yb)[(size_t)s0 * 256 + i];
  const ushort4 a1 = ((const ushort4*)Ya)[(size_t)s1 * 256 + i];
  const ushort4 b1 = ((const ushort4*)Yb)[(size_t)s1 * 256 + i];
  float4 r;
  r.x = g0 * (bf2f(a0.x) + bf2f(b0.x)) + g1 * (bf2f(a1.x) + bf2f(b1.x));
  r.y = g0 * (bf2f(a0.y) + bf2f(b0.y)) + g1 * (bf2f(a1.y) + bf2f(b1.y));
  r.z = g0 * (bf2f(a0.z) + bf2f(b0.z)) + g1 * (bf2f(a1.z) + bf2f(b1.z));
  r.w = g0 * (bf2f(a0.w) + bf2f(b0.w)) + g1 * (bf2f(a1.w) + bf2f(b1.w));
  ((float4*)out)[(size_t)t * 256 + i] = r;
}

extern "C" void kernel_launch(void* const* d_in, const int* in_sizes, int n_in,
                              void* d_out, int out_size, void* d_ws, size_t ws_size,
                              hipStream_t stream) {
  const float* x = (const float*)d_in[0];
  const float* Wr = (const float*)d_in[1];
  const float* W1 = (const float*)d_in[2];
  const float* b1 = (const float*)d_in[3];
  const float* W2 = (const float*)d_in[4];
  const float* b2 = (const float*)d_in[5];
  float* out = (float*)d_out;

  char* w = (char*)d_ws;
  size_t ob = 0;
  auto take = [&](size_t nbytes) -> void* {
    void* p = w + ob;
    ob = (ob + nbytes + 255) & ~(size_t)255;
    return p;
  };
  // Overlap: {W1T,Xg} (dead after GEMM1) share a region with {Ya,Yb} (bf16)
  unsigned short* W2T = (unsigned short*)take((size_t)NE * DM * DFF * 2);   // 64MB
  unsigned short* H = (unsigned short*)take((size_t)CAP * DFF * 2);         // 151MB
  char* R = (char*)take((size_t)NE * DFF * DM * 2 + (size_t)CAP * DM * 2);  // 100MB
  unsigned short* W1T = (unsigned short*)R;                                 // 64MB
  unsigned short* Xg = (unsigned short*)(R + (size_t)NE * DFF * DM * 2);    // 36MB
  unsigned short* Ya = (unsigned short*)R;                                  // 36MB
  unsigned short* Yb = (unsigned short*)(R + (size_t)CAP * DM * 2);         // 36MB
  unsigned* counts = (unsigned*)take(NE * 4);
  float* Psum = (float*)take(NE * 4);
  int* offs = (int*)take(16 * 4);
  int* tok_e = (int*)take(2 * N_TOK * 4);
  float* tok_g = (float*)take(2 * N_TOK * 4);
  int* tok_ls = (int*)take(2 * N_TOK * 4);
  int* tok_slot = (int*)take(2 * N_TOK * 4);
  (void)ws_size; (void)in_sizes; (void)n_in; (void)out_size;

  hipFuncSetAttribute(reinterpret_cast<const void*>(&gemmk<0, true, unsigned short>),
                      hipFuncAttributeMaxDynamicSharedMemorySize, 24576);
  hipFuncSetAttribute(reinterpret_cast<const void*>(&gemmk<1, false, unsigned short>),
                      hipFuncAttributeMaxDynamicSharedMemorySize, 49152);

  init_kernel<<<1, 64, 0, stream>>>(counts, Psum);
  router_kernel<<<N_TOK / 16, 256, 0, stream>>>(x, Wr, counts, Psum, tok_e, tok_g, tok_ls);
  transpose_cvt<<<dim3(DFF / 64, DM / 64, NE), 256, 0, stream>>>(W1, W1T, DM, DFF);
  transpose_cvt<<<dim3(DM / 64, DFF / 64, NE), 256, 0, stream>>>(W2, W2T, DFF, DM);
  offsets_kernel<<<1, 64, 0, stream>>>(counts, Psum, offs, out + (size_t)N_TOK * DM);
  gather_kernel<<<N_TOK, 256, 0, stream>>>(x, tok_e, tok_ls, offs, tok_slot, Xg);
  // GEMM1 (BM=256,BN=128): flat grid 72*32; XCD-banded by gr%8; B-LDS 24KB
  gemmk<0, true, unsigned short><<<dim3((CAP / 256) * 32), 512, 24576, stream>>>(
      Xg, W1T, b1, H, offs, DM, DFF, 0);
  // GEMM2 (BM=128,BN=256, split-K=2): flat grid 144*8; B-LDS 48KB
  gemmk<1, false, unsigned short><<<dim3((CAP / 128) * 8), 512, 49152, stream>>>(
      H, W2T, b2, Ya, offs, DFF, DM, (size_t)CAP * DM);
  combine_kernel<<<N_TOK, 256, 0, stream>>>(Ya, Yb, tok_slot, tok_g, out);
}

// Round 12
// 678.152 us; speedup vs baseline: 1.4818x; 1.4818x over previous
//
#include <hip/hip_runtime.h>
#include <cstdint>
#include <cstddef>

#define N_TOK 8192
#define DM 1024
#define DFF 4096
#define NE 8
#define PAD 256
#define CAP (N_TOK * 2 + NE * PAD)  // 18432

typedef __attribute__((ext_vector_type(8))) short bf16x8;
typedef __attribute__((ext_vector_type(4))) float f32x4;

__device__ __forceinline__ unsigned short f2bf(float f) {
  union { float f; unsigned u; } v; v.f = f;
  unsigned r = v.u + 0x7FFFu + ((v.u >> 16) & 1u);
  return (unsigned short)(r >> 16);
}
__device__ __forceinline__ float bf2f(unsigned short h) {
  union { unsigned u; float f; } v; v.u = ((unsigned)h) << 16;
  return v.f;
}

__device__ __forceinline__ void async16(unsigned short* l, const unsigned short* g) {
  __builtin_amdgcn_global_load_lds(
      (const __attribute__((address_space(1))) unsigned int*)g,
      (__attribute__((address_space(3))) unsigned int*)l, 16, 0, 0);
}

// ---------------- fused transpose + fp32->bf16 convert (both weights) --------
// z<8: W1 expert z (R=DM, C=DFF); z>=8: W2 expert z-8 (R=DFF, C=DM).
// Both have (C/64)*(R/64) = 1024 tiles -> flat blockIdx.x.
__global__ __launch_bounds__(256) void transpose_cvt2(
    const float* __restrict__ W1, const float* __restrict__ W2,
    unsigned short* __restrict__ W1T, unsigned short* __restrict__ W2T) {
  __shared__ float tile[64][65];
  const int z = blockIdx.z;
  const float* I;
  unsigned short* O;
  int R, C;
  if (z < 8) { I = W1 + (size_t)z * DM * DFF; O = W1T + (size_t)z * DM * DFF; R = DM; C = DFF; }
  else       { I = W2 + (size_t)(z - 8) * DM * DFF; O = W2T + (size_t)(z - 8) * DM * DFF; R = DFF; C = DM; }
  const int nbx = C >> 6;
  const int bx = blockIdx.x % nbx, by = blockIdx.x / nbx;
  const int r0 = by * 64, c0 = bx * 64;
  const int c = threadIdx.x & 63, r4 = threadIdx.x >> 6;
#pragma unroll
  for (int i = 0; i < 16; ++i) {
    int r = r4 * 16 + i;
    tile[r][c] = I[(size_t)(r0 + r) * C + c0 + c];
  }
  __syncthreads();
#pragma unroll
  for (int i = 0; i < 16; ++i) {
    int r = r4 * 16 + i;
    O[(size_t)(c0 + r) * R + r0 + c] = f2bf(tile[c][r]);
  }
}

// ---------------- router ----------------
__global__ __launch_bounds__(256) void router_kernel(
    const float* __restrict__ x, const float* __restrict__ Wr,
    unsigned* __restrict__ counts, float* __restrict__ Psum,
    int* __restrict__ tok_e, float* __restrict__ tok_g, int* __restrict__ tok_ls) {
  __shared__ float ps[NE];
  const int tid = threadIdx.x;
  if (tid < NE) ps[tid] = 0.f;
  __syncthreads();
  const int lane = tid & 63, wid = tid >> 6;
  for (int u = 0; u < 4; ++u) {
    const int t = blockIdx.x * 16 + wid * 4 + u;
    float a[NE];
#pragma unroll
    for (int e = 0; e < NE; ++e) a[e] = 0.f;
#pragma unroll
    for (int i = 0; i < 16; ++i) {
      const int d = i * 64 + lane;
      const float xv = x[(size_t)t * DM + d];
      const float* wr = &Wr[(size_t)d * NE];
#pragma unroll
      for (int e = 0; e < NE; ++e) a[e] = fmaf(xv, wr[e], a[e]);
    }
#pragma unroll
    for (int e = 0; e < NE; ++e)
      for (int s = 32; s > 0; s >>= 1) a[e] += __shfl_xor(a[e], s);
    float mx = a[0];
#pragma unroll
    for (int e = 1; e < NE; ++e) mx = fmaxf(mx, a[e]);
    float p[NE], s = 0.f;
#pragma unroll
    for (int e = 0; e < NE; ++e) { p[e] = expf(a[e] - mx); s += p[e]; }
    float q[NE];
#pragma unroll
    for (int e = 0; e < NE; ++e) q[e] = p[e] / s;
    int i0 = 0; float b0 = q[0];
#pragma unroll
    for (int e = 1; e < NE; ++e) if (q[e] > b0) { b0 = q[e]; i0 = e; }
    int i1 = -1; float b1v = -1.f;
#pragma unroll
    for (int e = 0; e < NE; ++e) if (e != i0 && q[e] > b1v) { b1v = q[e]; i1 = e; }
    const float gs = q[i0] + q[i1];
    const float g0 = q[i0] / gs, g1 = q[i1] / gs;
    if (lane == 0) {
#pragma unroll
      for (int e = 0; e < NE; ++e) atomicAdd(&ps[e], q[e]);
      const int ls0 = (int)atomicAdd(&counts[i0], 1u);
      const int ls1 = (int)atomicAdd(&counts[i1], 1u);
      tok_e[2 * t] = i0; tok_e[2 * t + 1] = i1;
      tok_g[2 * t] = g0; tok_g[2 * t + 1] = g1;
      tok_ls[2 * t] = ls0; tok_ls[2 * t + 1] = ls1;
    }
  }
  __syncthreads();
  if (tid < NE) atomicAdd(&Psum[tid], ps[tid]);
}

// ---------------- offsets (256-padded prefix) + total + aux loss ----------------
__global__ void offsets_kernel(const unsigned* __restrict__ counts,
                               const float* __restrict__ Psum,
                               int* __restrict__ offs, float* __restrict__ aux_out) {
  if (threadIdx.x == 0 && blockIdx.x == 0) {
    int o = 0; float aux = 0.f;
    for (int e = 0; e < NE; ++e) {
      offs[e] = o;
      o += (int)((counts[e] + (PAD - 1u)) / PAD) * PAD;
      aux += ((float)counts[e] / (float)N_TOK) * (Psum[e] / (float)N_TOK);
    }
    offs[NE] = o;  // total padded rows
    aux_out[0] = 0.01f * (float)NE * aux;
  }
}

// ---------------- gather ----------------
__global__ __launch_bounds__(256) void gather_kernel(
    const float* __restrict__ x, const int* __restrict__ tok_e,
    const int* __restrict__ tok_ls, const int* __restrict__ offs,
    int* __restrict__ tok_slot, unsigned short* __restrict__ Xg) {
  const int t = blockIdx.x;
  __shared__ int ss[2];
  if (threadIdx.x < 2) {
    const int k = threadIdx.x;
    const int e = tok_e[2 * t + k];
    const int sl = offs[e] + tok_ls[2 * t + k];
    ss[k] = sl;
    tok_slot[2 * t + k] = sl;
  }
  __syncthreads();
  const int i = threadIdx.x;
  const float4 v = ((const float4*)x)[(size_t)t * 256 + i];
  ushort4 h;
  h.x = f2bf(v.x); h.y = f2bf(v.y); h.z = f2bf(v.z); h.w = f2bf(v.w);
  ((ushort4*)Xg)[(size_t)ss[0] * 256 + i] = h;
  ((ushort4*)Xg)[(size_t)ss[1] * 256 + i] = h;
}

// ---------------- shape-templated GEMM, BK=32, ring-3, 2 blocks/CU -----------
// R12: reverted to R10's staged A+B ring-3 (R11's A-direct exposed global-load
// latency per tile -> 397us). BMODE 0: BM=256,BN=128,SPLIT=1, 2D grid x=tn
// y=gr NON-banded (R9/R10 A/B: banding GEMM1 raised FETCH 204->315MB, no win).
// BMODE 1: BM=128,BN=256,SPLIT=2, flat XCD-banded grid (R9/R10: banding cut
// GEMM2 FETCH 448->315MB). 512 thr = 8 waves, wave tile 64x64, acc 64 regs ->
// 4 waves/SIMD, 2 blocks/CU @ 72KB LDS.
// LDS: A ring 3 x [BM x 32] bf16, B ring 3 x [BN x 32]; 16B chunks XOR-swizzled
// by ((row>>1)&3) both sides (64B rows, bijective, residual 2-way = free).
// Per K-tile: 8 ds_read_b128 + 16 MFMA + 3 stage loads + vmcnt(3) + 1 barrier.
// Ring ledger (R8-R10 proven): at T read buf d0, stage T+2 into d2 (last read
// T-1, >=1 barrier back); vmcnt(3) retires T+1's loads. Counted, never 0.
// tanh-GELU (sigmoid form, inf-safe) -- R10-validated, absmax unchanged.
template <int BMODE, bool GELU, typename CT>
__global__ __launch_bounds__(512, 4) void gemmk(
    const unsigned short* __restrict__ Ag, const unsigned short* __restrict__ Bt,
    const float* __restrict__ bias, CT* __restrict__ Cout,
    const int* __restrict__ offs, const int K, const int Nn,
    const size_t c_split_stride) {
  constexpr int BM = (BMODE == 0) ? 256 : 128;
  constexpr int BN = (BMODE == 0) ? 128 : 256;
  constexpr int WN = BN / 64;                  // waves along N
  constexpr int AREG = BM * 32;                // shorts per A ring entry
  constexpr int BREG = BN * 32;                // shorts per B ring entry
  constexpr int SPLIT = (BMODE == 0) ? 1 : 2;

  int tn, gr, ks;
  if (BMODE == 0) {
    tn = (int)blockIdx.x; gr = (int)blockIdx.y; ks = 0;   // 2D, tn fast
  } else {
    const int flat = (int)blockIdx.x;                     // XCD-banded flat
    const int xr = flat & 7;
    const int rest = flat >> 3;
    tn = rest & 3; ks = (rest >> 2) & 1; gr = ((rest >> 3) << 3) + xr;
  }

  const int grow = gr * BM;
  if (grow >= offs[NE]) return;
  int e = 0;
#pragma unroll
  for (int k = 1; k < NE; ++k) if (offs[k] <= grow) e = k;
  const int kext = K / SPLIT;
  const int nt = kext >> 5;  // K-tiles of 32

  const unsigned short* A = Ag + (size_t)grow * K + (size_t)ks * kext;
  const unsigned short* B = Bt + ((size_t)e * Nn + (size_t)tn * BN) * K + (size_t)ks * kext;
  const float* bp = (ks == 0) ? bias : nullptr;
  CT* Cw = Cout + (size_t)ks * c_split_stride;

  extern __shared__ unsigned short lds[];
  unsigned short* LA = lds;                  // 3 x AREG
  unsigned short* LB = lds + 3 * AREG;       // 3 x BREG

  const int tid = threadIdx.x;
  const int lane = tid & 63;
  const int wid = tid >> 6;
  const int wm = wid / WN;
  const int wn = wid % WN;
  const int arow = lane & 15;
  const int kc = lane >> 4;   // 16B chunk 0..3 within 32-short row

  // LDS read addressing: swizzled chunk (kc ^ ((row>>1)&3)); row%8 == arow%8.
  const int sc = ((kc ^ ((arow >> 1) & 3)) << 3);
  const int aBase = (wm * 64 + arow) * 32 + sc;   // + mf*512
  const int bBase = (wn * 64 + arow) * 32 + sc;   // + nf*512

  // stage addressing: chunk c = call*512 + tid; r = c>>2; src chunk
  // (tid&3)^((r>>1)&3) = (tid&3)^((tid>>3)&3) (call adds 128 rows = 0 mod 8).
  const int swzs = (((tid & 3) ^ ((tid >> 3) & 3)) << 3);
  const unsigned short* sA = A + (size_t)(tid >> 2) * K + swzs;
  const unsigned short* sB = B + (size_t)(tid >> 2) * K + swzs;
  const size_t r128 = (size_t)128 * K;
  const size_t dstw = (size_t)wid * 512;  // shorts; lane*16B added by HW

  auto stgA = [&](int db, size_t kt) {
    async16(LA + db * AREG + dstw, sA + kt);
    if constexpr (BMODE == 0) async16(LA + db * AREG + 4096 + dstw, sA + r128 + kt);
  };
  auto stgB = [&](int db, size_t kt) {
    async16(LB + db * BREG + dstw, sB + kt);
    if constexpr (BMODE == 1) async16(LB + db * BREG + 4096 + dstw, sB + r128 + kt);
  };

  f32x4 acc[4][4];
#pragma unroll
  for (int m = 0; m < 4; ++m)
#pragma unroll
    for (int n = 0; n < 4; ++n) acc[m][n] = (f32x4){0.f, 0.f, 0.f, 0.f};

  // prologue: stage T0 -> buf0, T1 -> buf1; wait T0 (counted), barrier.
  stgA(0, 0); stgB(0, 0);
  stgA(1, 32); stgB(1, 32);
  asm volatile("s_waitcnt vmcnt(3)" ::: "memory");
  asm volatile("s_barrier" ::: "memory");

  int d0 = 0;
  for (int T = 0; T < nt; ++T) {
    const int d2 = (d0 >= 1) ? d0 - 1 : d0 + 2;  // (d0+2)%3
    const size_t kt2 = (size_t)((T + 2 < nt) ? T + 2 : 0) << 5;
    const int la = d0 * AREG, lb = d0 * BREG;

    bf16x8 afr[4], bfr[4];
#pragma unroll
    for (int mf = 0; mf < 4; ++mf) afr[mf] = *(const bf16x8*)&LA[la + aBase + mf * 512];
#pragma unroll
    for (int nf = 0; nf < 4; ++nf) bfr[nf] = *(const bf16x8*)&LB[lb + bBase + nf * 512];

    stgA(d2, kt2);
    stgB(d2, kt2);

    __builtin_amdgcn_s_setprio(1);
#pragma unroll
    for (int m = 0; m < 4; ++m)
#pragma unroll
      for (int n = 0; n < 4; ++n)
        acc[m][n] = __builtin_amdgcn_mfma_f32_16x16x32_bf16(afr[m], bfr[n], acc[m][n], 0, 0, 0);
    __builtin_amdgcn_s_setprio(0);

    asm volatile("s_waitcnt vmcnt(3)" ::: "memory");
    asm volatile("s_barrier" ::: "memory");
    d0 = (d0 == 2) ? 0 : d0 + 1;
  }
  asm volatile("s_waitcnt vmcnt(0)" ::: "memory");

  // epilogue: n innermost -> each output line completed back-to-back (no RMW).
  const int rl = (lane >> 4) * 4;
  const int cl = lane & 15;
  float bv[4];
#pragma unroll
  for (int n = 0; n < 4; ++n) {
    const int col = tn * BN + wn * 64 + n * 16 + cl;
    bv[n] = bp ? bp[(size_t)e * Nn + col] : 0.f;
  }
#pragma unroll
  for (int m = 0; m < 4; ++m) {
    const int row = grow + wm * 64 + m * 16 + rl;
#pragma unroll
    for (int jj = 0; jj < 4; ++jj) {
      CT* rowp = Cw + (size_t)(row + jj) * Nn + tn * BN + wn * 64 + cl;
#pragma unroll
      for (int n = 0; n < 4; ++n) {
        float v = acc[m][n][jj] + bv[n];
        if (GELU) {
          // tanh-approx GELU, sigmoid form (inf-safe)
          const float w = -1.5957691216057308f * (v + 0.044715f * v * v * v);
          v = v / (1.f + __expf(w));
        }
        if constexpr (sizeof(CT) == 2) { rowp[n * 16] = (CT)f2bf(v); } else { rowp[n * 16] = (CT)v; }
      }
    }
  }
}

// ---------------- combine: out[t] = g0*(Ya+Yb)[s0] + g1*(Ya+Yb)[s1], Y bf16 --
__global__ __launch_bounds__(256) void combine_kernel(
    const unsigned short* __restrict__ Ya, const unsigned short* __restrict__ Yb,
    const int* __restrict__ tok_slot, const float* __restrict__ tok_g,
    float* __restrict__ out) {
  const int t = blockIdx.x;
  const int i = threadIdx.x;
  const int s0 = tok_slot[2 * t], s1 = tok_slot[2 * t + 1];
  const float g0 = tok_g[2 * t], g1 = tok_g[2 * t + 1];
  const ushort4 a0 = ((const ushort4*)Ya)[(size_t)s0 * 256 + i];
  const ushort4 b0 = ((const ushort4*)Yb)[(size_t)s0 * 256 + i];
  const ushort4 a1 = ((const ushort4*)Ya)[(size_t)s1 * 256 + i];
  const ushort4 b1 = ((const ushort4*)Yb)[(size_t)s1 * 256 + i];
  float4 r;
  r.x = g0 * (bf2f(a0.x) + bf2f(b0.x)) + g1 * (bf2f(a1.x) + bf2f(b1.x));
  r.y = g0 * (bf2f(a0.y) + bf2f(b0.y)) + g1 * (bf2f(a1.y) + bf2f(b1.y));
  r.z = g0 * (bf2f(a0.z) + bf2f(b0.z)) + g1 * (bf2f(a1.z) + bf2f(b1.z));
  r.w = g0 * (bf2f(a0.w) + bf2f(b0.w)) + g1 * (bf2f(a1.w) + bf2f(b1.w));
  ((float4*)out)[(size_t)t * 256 + i] = r;
}

extern "C" void kernel_launch(void* const* d_in, const int* in_sizes, int n_in,
                              void* d_out, int out_size, void* d_ws, size_t ws_size,
                              hipStream_t stream) {
  const float* x = (const float*)d_in[0];
  const float* Wr = (const float*)d_in[1];
  const float* W1 = (const float*)d_in[2];
  const float* b1 = (const float*)d_in[3];
  const float* W2 = (const float*)d_in[4];
  const float* b2 = (const float*)d_in[5];
  float* out = (float*)d_out;

  char* w = (char*)d_ws;
  size_t ob = 0;
  auto take = [&](size_t nbytes) -> void* {
    void* p = w + ob;
    ob = (ob + nbytes + 255) & ~(size_t)255;
    return p;
  };
  // Overlap: {W1T,Xg} (dead after GEMM1) share a region with {Ya,Yb} (bf16)
  unsigned short* W2T = (unsigned short*)take((size_t)NE * DM * DFF * 2);   // 64MB
  unsigned short* H = (unsigned short*)take((size_t)CAP * DFF * 2);         // 151MB
  char* R = (char*)take((size_t)NE * DFF * DM * 2 + (size_t)CAP * DM * 2);  // 100MB
  unsigned short* W1T = (unsigned short*)R;                                 // 64MB
  unsigned short* Xg = (unsigned short*)(R + (size_t)NE * DFF * DM * 2);    // 36MB
  unsigned short* Ya = (unsigned short*)R;                                  // 36MB
  unsigned short* Yb = (unsigned short*)(R + (size_t)CAP * DM * 2);         // 36MB
  char* cz = (char*)take(64);  // counts (8x u32) + Psum (8x f32), memset-zeroed
  unsigned* counts = (unsigned*)cz;
  float* Psum = (float*)(cz + 32);
  int* offs = (int*)take(16 * 4);
  int* tok_e = (int*)take(2 * N_TOK * 4);
  float* tok_g = (float*)take(2 * N_TOK * 4);
  int* tok_ls = (int*)take(2 * N_TOK * 4);
  int* tok_slot = (int*)take(2 * N_TOK * 4);
  (void)ws_size; (void)in_sizes; (void)n_in; (void)out_size;

  hipFuncSetAttribute(reinterpret_cast<const void*>(&gemmk<0, true, unsigned short>),
                      hipFuncAttributeMaxDynamicSharedMemorySize, 73728);
  hipFuncSetAttribute(reinterpret_cast<const void*>(&gemmk<1, false, unsigned short>),
                      hipFuncAttributeMaxDynamicSharedMemorySize, 73728);

  hipMemsetAsync(cz, 0, 64, stream);
  router_kernel<<<N_TOK / 16, 256, 0, stream>>>(x, Wr, counts, Psum, tok_e, tok_g, tok_ls);
  transpose_cvt2<<<dim3(1024, 1, 16), 256, 0, stream>>>(W1, W2, W1T, W2T);
  offsets_kernel<<<1, 64, 0, stream>>>(counts, Psum, offs, out + (size_t)N_TOK * DM);
  gather_kernel<<<N_TOK, 256, 0, stream>>>(x, tok_e, tok_ls, offs, tok_slot, Xg);
  // GEMM1 (BM=256,BN=128): 2D grid x=tn(32) fast, y=72 row-tiles (non-banded)
  gemmk<0, true, unsigned short><<<dim3(32, CAP / 256), 512, 73728, stream>>>(
      Xg, W1T, b1, H, offs, DM, DFF, 0);
  // GEMM2 (BM=128,BN=256, split-K=2): XCD-banded flat grid 144*8; halves Ya/Yb
  gemmk<1, false, unsigned short><<<dim3((CAP / 128) * 8), 512, 73728, stream>>>(
      H, W2T, b2, Ya, offs, DFF, DM, (size_t)CAP * DM);
  combine_kernel<<<N_TOK, 256, 0, stream>>>(Ya, Yb, tok_slot, tok_g, out);
}